// Round 11
// baseline (594.646 us; speedup 1.0000x reference)
//
#include <hip/hip_runtime.h>
#include <stdint.h>

// ---------------- types / helpers ----------------
typedef short bf16x8 __attribute__((ext_vector_type(8)));
typedef float f32x4 __attribute__((ext_vector_type(4)));

#define AS1 __attribute__((address_space(1)))
#define AS3 __attribute__((address_space(3)))

static __device__ __forceinline__ void gl16(const void* g, void* l) {
  __builtin_amdgcn_global_load_lds((const AS1 void*)g, (AS3 void*)l, 16, 0, 0);
}

static __device__ __forceinline__ unsigned short f2bf(float f) {
  unsigned u = __float_as_uint(f);
  u = u + 0x7fffu + ((u >> 16) & 1u);
  return (unsigned short)(u >> 16);
}
static __device__ __forceinline__ float bf2f(unsigned short h) {
  return __uint_as_float(((unsigned)h) << 16);
}
static __device__ __forceinline__ float mishf(float x) {
  float sp = fmaxf(x, 0.f) + log1pf(expf(-fabsf(x)));
  float e2 = expf(-2.f * sp);
  float th = (1.f - e2) / (1.f + e2);
  return x * th;
}

// geometry
#define NIMG 8
#define HH 128
#define WW 128
#define HP 130
#define CIN 256
#define MPIX (NIMG * HH * WW)       // 131072
#define KTOT 2304                   // 72 slices of 32 (36 steps of 64)
#define FGCNT (MPIX * 9)            // 1179648
#define TSCNT (MPIX * 9 * 4)        // 4718592

__device__ __constant__ float AW[9] = {456.f, 912.f, 1824.f, 320.f, 640.f, 1280.f, 224.f, 448.f, 896.f};
__device__ __constant__ float AH[9] = {224.f, 448.f, 896.f, 320.f, 640.f, 1280.f, 448.f, 896.f, 1792.f};

// ---------------- K0a: conv weights -> Wt2[slice][oc][32] bf16, slice = icb*9 + kh*3 + kw ----------------
__global__ __launch_bounds__(256) void k_wt(const float* __restrict__ Wb,
                                            unsigned short* __restrict__ Wt2) {
  int d = blockIdx.x * 256 + threadIdx.x;  // 589824 = 72*256*32
  int c = d & 31, oc = (d >> 5) & 255, s = d >> 13;
  int icb = s / 9, khw = s % 9, kh = khw / 3, kw = khw % 3;
  int ic = icb * 32 + c;
  Wt2[d] = f2bf(Wb[((oc * 256 + ic) * 3 + kh) * 3 + kw]);
}

// ---------------- K0b: x (NCHW f32) -> xt2 (channel-blocked padded) interior ----------------
// xt2 layout: [icb(8)*8+n][130][130][32] bf16
__global__ __launch_bounds__(256) void k_tr(const float* __restrict__ x,
                                            unsigned short* __restrict__ xt2) {
  __shared__ float tile[32][129];
  int b = blockIdx.x;  // 8 n * 128 h * 8 icb = 8192
  int icb = b & 7, h = (b >> 3) & 127, n = b >> 10;
  int t = threadIdx.x;
  const float* src = x + (((size_t)(n * 256 + icb * 32) * 128 + h) * 128);
#pragma unroll
  for (int i = 0; i < 4; ++i) {
    int idx = t + 256 * i;          // 1024 float4 units
    int w4 = idx & 31, ic = idx >> 5;
    float4 v = *(const float4*)(src + (size_t)ic * 16384 + w4 * 4);
    tile[ic][w4 * 4 + 0] = v.x; tile[ic][w4 * 4 + 1] = v.y;
    tile[ic][w4 * 4 + 2] = v.z; tile[ic][w4 * 4 + 3] = v.w;
  }
  __syncthreads();
#pragma unroll
  for (int i = 0; i < 8; ++i) {
    int idx = t + 256 * i;          // 2048 bf16-pairs
    int icp = idx & 15, w = idx >> 4;
    unsigned lo = f2bf(tile[icp * 2][w]);
    unsigned hi = f2bf(tile[icp * 2 + 1][w]);
    size_t pix = ((size_t)(icb * 8 + n) * HP + (h + 1)) * HP + (w + 1);
    *(unsigned*)(xt2 + pix * 32 + icp * 2) = lo | (hi << 16);
  }
}

// ---------------- K0c: zero padded borders of xt2 ----------------
__global__ __launch_bounds__(256) void k_bord(unsigned short* __restrict__ xt2) {
  int tid = blockIdx.x * 256 + threadIdx.x;  // 64 planes * 516 border pix * 4 chunks = 132096
  int chunk = tid & 3, pix = tid >> 2;
  int nn = pix / 516, bp = pix % 516;        // nn = icb*8+n plane
  int hp, wp;
  if (bp < 130) { hp = 0; wp = bp; }
  else if (bp < 260) { hp = 129; wp = bp - 130; }
  else { int r = bp - 260; hp = 1 + (r >> 1); wp = (r & 1) ? 129 : 0; }
  size_t off = (((size_t)nn * HP + hp) * HP + wp) * 32 + chunk * 8;
  uint4 z = {0u, 0u, 0u, 0u};
  *(uint4*)(xt2 + off) = z;
}

// ---------------- K1: conv3x3 implicit GEMM — BK=64, 36 steps ----------------
// R5/R8/R9/R10 all pinned at ~373us across four different schedules -> the
// constraint is FIXED PER-BARRIER-STEP LATENCY (~3900 cyc/block-step), matching
// m102's shape curve (320 TF @ 64 K-steps for this structure). R11: halve the
// step count. BK=64: 36 steps of {8 gl16, 16 ds_read_b128, 32 MFMA}/wave.
// LDS 32KB single buffer: A [kc(2)][region(8)][1KB] | B same at +16KB.
// Region-major (0-conflict, R8-proven): byte = kc*8192 + r*1024 + q*256 + i16*16.
// Plain 2-barrier schedule, compiler-scheduled (m141 lesson). Occupancy ~3
// blocks/CU (LDS 32KB, ~160 regs). Each 32-slice decodes (icb,kh,kw)
// independently (kc pair may cross an icb plane boundary).
__global__ __launch_bounds__(256) void k_conv(const unsigned short* __restrict__ xt2,
                                              const unsigned short* __restrict__ Wt2,
                                              const float* __restrict__ b_base,
                                              unsigned short* __restrict__ yt2,
                                              float* __restrict__ statsA) {
  __shared__ __align__(16) char lds[32768];    // A 16KB | B 16KB
  int t = threadIdx.x;
  int lane = t & 63, w4 = t >> 6;              // 4 waves
  int wr = w4 >> 1, wc = w4 & 1;               // 2M x 2N wave grid, wave tile 64x64
  int row16 = lane & 15, kgl = lane >> 4;
  int pr = lane & 15, pq = lane >> 4;          // staging lane decomposition

  int bid = blockIdx.x;                        // 2048, %8==0 -> bijective
  int swz = (bid & 7) * 256 + (bid >> 3);      // XCD k owns contiguous 256 tiles
  int pixb = swz >> 1, oh = swz & 1;
  int n = pixb >> 7, h0 = pixb & 127;
  size_t M0 = (size_t)pixb * 128;

  f32x4 acc[4][4];
#pragma unroll
  for (int m = 0; m < 4; ++m)
#pragma unroll
    for (int nf = 0; nf < 4; ++nf) { f32x4 z = {0.f, 0.f, 0.f, 0.f}; acc[m][nf] = z; }

  // A: wave w4 stages regions 2w4, 2w4+1 of each kc-half (pixels 32w4 .. +31)
  const unsigned short* aS0 =
      xt2 + ((size_t)(n * HP + h0) * HP + w4 * 32 + pr) * 32 + pq * 8;
  const unsigned short* aS1 = aS0 + 16 * 32;
  // B: wave w4 stages regions 2w4, 2w4+1 of each kc-half (ocs oh*128 + 32w4 .. +31)
  const unsigned short* bS0 = Wt2 + (size_t)(oh * 128 + w4 * 32 + pr) * 32 + pq * 8;
  const unsigned short* bS1 = bS0 + 16 * 32;

  const size_t planeStride = (size_t)8 * HP * HP * 32;
  int aoffA = wr * 4096 + kgl * 256 + row16 * 16;   // + m*1024, + kc*8192
  int aoffB = wc * 4096 + kgl * 256 + row16 * 16;   // + nf*1024, + kc*8192

  // decode one 32-slice: slice = icb*9 + kh*3 + kw  -> A-plane offset
  auto aoff32 = [&](int sl) -> size_t {
    int icb_ = (sl * 57) >> 9;         // sl/9 for sl<512
    int khw = sl - icb_ * 9;
    int kh_ = (khw * 11) >> 5;         // khw/3 for khw<9
    int kw_ = khw - kh_ * 3;
    return (size_t)icb_ * planeStride + ((size_t)kh_ * HP + kw_) * 32;
  };

  for (int s = 0; s < 36; ++s) {
#pragma unroll
    for (int kc = 0; kc < 2; ++kc) {
      int sl = 2 * s + kc;
      size_t offA = aoff32(sl);
      size_t offB = (size_t)sl * 8192;   // 256 oc * 32 shorts per slice
      char* bufA = lds + kc * 8192;
      char* bufB = lds + 16384 + kc * 8192;
      gl16(aS0 + offA, bufA + (2 * w4) * 1024);
      gl16(aS1 + offA, bufA + (2 * w4 + 1) * 1024);
      gl16(bS0 + offB, bufB + (2 * w4) * 1024);
      gl16(bS1 + offB, bufB + (2 * w4 + 1) * 1024);
    }
    __syncthreads();
    bf16x8 af[4][2], bfr[4][2];
#pragma unroll
    for (int kc = 0; kc < 2; ++kc) {
#pragma unroll
      for (int m = 0; m < 4; ++m)
        af[m][kc] = *(const bf16x8*)(lds + kc * 8192 + aoffA + m * 1024);
#pragma unroll
      for (int nf = 0; nf < 4; ++nf)
        bfr[nf][kc] = *(const bf16x8*)(lds + 16384 + kc * 8192 + aoffB + nf * 1024);
    }
#pragma unroll
    for (int m = 0; m < 4; ++m)
#pragma unroll
      for (int nf = 0; nf < 4; ++nf) {
        acc[m][nf] = __builtin_amdgcn_mfma_f32_16x16x32_bf16(af[m][0], bfr[nf][0], acc[m][nf], 0, 0, 0);
        acc[m][nf] = __builtin_amdgcn_mfma_f32_16x16x32_bf16(af[m][1], bfr[nf][1], acc[m][nf], 0, 0, 0);
      }
    __syncthreads();
  }

  // epilogue: bias + mish, store channel-blocked yt2[oc>>5][pix][oc&31], stats
  float sums[4] = {0.f, 0.f, 0.f, 0.f}, sumq[4] = {0.f, 0.f, 0.f, 0.f};
#pragma unroll
  for (int nf = 0; nf < 4; ++nf) {
    int oc = oh * 128 + wc * 64 + nf * 16 + row16;
    float bias = b_base[oc];
    size_t obase = (size_t)(oc >> 5) * MPIX * 32 + (oc & 31);
#pragma unroll
    for (int m = 0; m < 4; ++m) {
#pragma unroll
      for (int j = 0; j < 4; ++j) {
        int p = wr * 64 + m * 16 + kgl * 4 + j;
        float y = mishf(acc[m][nf][j] + bias);
        yt2[obase + (M0 + p) * 32] = f2bf(y);
        sums[nf] += y; sumq[nf] += y * y;
      }
    }
  }
#pragma unroll
  for (int nf = 0; nf < 4; ++nf) {
    float s1 = sums[nf], s2 = sumq[nf];
    s1 += __shfl_xor(s1, 16); s2 += __shfl_xor(s2, 16);
    s1 += __shfl_xor(s1, 32); s2 += __shfl_xor(s2, 32);
    if (lane < 16) {
      int oc = oh * 128 + wc * 64 + nf * 16 + lane;
      atomicAdd(&statsA[oc], s1);
      atomicAdd(&statsA[256 + oc], s2);
    }
  }
}

// ---------------- K2: finalize base BN, fold into fused 1x1 weights ----------------
// W2t2 layout: [s(8)][64 oc][32] bf16
__global__ __launch_bounds__(256) void k_fold(const float* __restrict__ statsA,
                                              const float* __restrict__ g_base,
                                              const float* __restrict__ be_base,
                                              const float* __restrict__ W_cls,
                                              const float* __restrict__ b_cls,
                                              const float* __restrict__ W_reg,
                                              const float* __restrict__ b_reg,
                                              unsigned short* __restrict__ W2t2,
                                              float* __restrict__ b2) {
  __shared__ float sS[256], sT[256];
  int t = threadIdx.x;
  {
    float cnt = (float)MPIX;
    float m = statsA[t] / cnt;
    float v = fmaxf(statsA[256 + t] / cnt - m * m, 0.f);
    float s = g_base[t] * rsqrtf(v + 1e-5f);
    sS[t] = s;
    sT[t] = be_base[t] - m * s;
  }
  __syncthreads();
  if (t < 64) {
    float bias = 0.f;
    if (t < 36) bias = b_reg[t];
    else if (t < 54) bias = b_cls[t - 36];
    float acc = 0.f;
    for (int ic = 0; ic < 256; ++ic) {
      float w = 0.f;
      if (t < 36) w = W_reg[t * 256 + ic];
      else if (t < 54) w = W_cls[(t - 36) * 256 + ic];
      acc += w * sT[ic];
      W2t2[((size_t)(ic >> 5) * 64 + t) * 32 + (ic & 31)] = f2bf(w * sS[ic]);
    }
    b2[t] = bias + acc;
  }
}

// ---------------- K3: fused 1x1 heads GEMM (M=131072, N=64, K=256) + z stats ----------------
// Region-major LDS + 2-phase dbuf. 4 waves, 24KB LDS.
__global__ __launch_bounds__(256) void k_mm2(const unsigned short* __restrict__ yt2,
                                             const unsigned short* __restrict__ W2t2,
                                             const float* __restrict__ b2,
                                             unsigned short* __restrict__ zt,
                                             float* __restrict__ statsZ) {
  __shared__ __align__(16) char lds2[24576];   // 2 x (A 8KB | B 4KB)
  int t = threadIdx.x, lane = t & 63, w4 = t >> 6;   // 4 waves
  int row16 = lane & 15, kgl = lane >> 4;
  int pr = lane & 15, pq = lane >> 4;
  size_t pixbase = (size_t)blockIdx.x * 128;

  f32x4 acc[2][4];
#pragma unroll
  for (int m = 0; m < 2; ++m)
#pragma unroll
    for (int nn = 0; nn < 4; ++nn) { f32x4 z = {0.f, 0.f, 0.f, 0.f}; acc[m][nn] = z; }

  // A: wave w4 stages regions 2w4, 2w4+1 (pixels 32w4 .. +31)
  const unsigned short* aS0 = yt2 + (pixbase + w4 * 32 + pr) * 32 + pq * 8;
  const unsigned short* aS1 = aS0 + 16 * 32;
  // B: wave w4 stages region w4 (ocs 16w4 .. +15)
  const unsigned short* bS = W2t2 + (size_t)(w4 * 16 + pr) * 32 + pq * 8;

  int aoffA = w4 * 2048 + kgl * 256 + row16 * 16;  // + m*1024
  int aoffB = kgl * 256 + row16 * 16;              // + nn*1024

  auto STG = [&](int s, int c_) {
    size_t ao = (size_t)s * MPIX * 32;
    size_t bo = (size_t)s * 2048;          // 64 oc * 32
    char* buf = lds2 + c_ * 12288;
    gl16(aS0 + ao, buf + (2 * w4) * 1024);
    gl16(aS1 + ao, buf + (2 * w4 + 1) * 1024);
    gl16(bS + bo, buf + 8192 + w4 * 1024);
  };

  STG(0, 0);
  int cur = 0;
  for (int s = 0; s < 8; ++s) {
    __syncthreads();
    if (s < 7) STG(s + 1, cur ^ 1);
    const char* ab = lds2 + cur * 12288;
    const char* bb = ab + 8192;
    bf16x8 af[2], bfr[4];
#pragma unroll
    for (int m = 0; m < 2; ++m) af[m] = *(const bf16x8*)(ab + aoffA + m * 1024);
#pragma unroll
    for (int nn = 0; nn < 4; ++nn) bfr[nn] = *(const bf16x8*)(bb + aoffB + nn * 1024);
#pragma unroll
    for (int m = 0; m < 2; ++m)
#pragma unroll
      for (int nn = 0; nn < 4; ++nn)
        acc[m][nn] = __builtin_amdgcn_mfma_f32_16x16x32_bf16(af[m], bfr[nn], acc[m][nn], 0, 0, 0);
    cur ^= 1;
  }

  float sums[4] = {0.f, 0.f, 0.f, 0.f}, sumq[4] = {0.f, 0.f, 0.f, 0.f};
#pragma unroll
  for (int nn = 0; nn < 4; ++nn) {
    int oc = nn * 16 + row16;
    float bias = b2[oc];
#pragma unroll
    for (int m = 0; m < 2; ++m) {
#pragma unroll
      for (int j = 0; j < 4; ++j) {
        int p = w4 * 32 + m * 16 + kgl * 4 + j;
        float v = acc[m][nn][j] + bias;
        zt[(pixbase + p) * 64 + oc] = f2bf(v);
        sums[nn] += v; sumq[nn] += v * v;
      }
    }
  }
#pragma unroll
  for (int nn = 0; nn < 4; ++nn) {
    float s1 = sums[nn], s2 = sumq[nn];
    s1 += __shfl_xor(s1, 16); s2 += __shfl_xor(s2, 16);
    s1 += __shfl_xor(s1, 32); s2 += __shfl_xor(s2, 32);
    if (lane < 16) {
      int oc = nn * 16 + lane;
      atomicAdd(&statsZ[oc], s1);
      atomicAdd(&statsZ[64 + oc], s2);
    }
  }
}

// ---------------- K4: finalize z BN scale/shift ----------------
__global__ __launch_bounds__(64) void k_zstat(const float* __restrict__ statsZ,
                                              const float* __restrict__ g_cls,
                                              const float* __restrict__ be_cls,
                                              const float* __restrict__ g_reg,
                                              const float* __restrict__ be_reg,
                                              float* __restrict__ zsc,
                                              float* __restrict__ zsh) {
  int t = threadIdx.x;  // 64
  float g = 1.f, be = 0.f;
  if (t < 36) { g = g_reg[t]; be = be_reg[t]; }
  else if (t < 54) { g = g_cls[t - 36]; be = be_cls[t - 36]; }
  float cnt = (float)MPIX;
  float m = statsZ[t] / cnt;
  float v = fmaxf(statsZ[64 + t] / cnt - m * m, 0.f);
  float s = g * rsqrtf(v + 1e-5f);
  zsc[t] = s;
  zsh[t] = be - m * s;
}

// ---------------- K5: BN-apply + softmax + anchor decode + outputs ----------------
__global__ __launch_bounds__(256) void k_dec(const unsigned short* __restrict__ zt,
                                             const float* __restrict__ zsc,
                                             const float* __restrict__ zsh,
                                             const int* __restrict__ imgsz,
                                             float* __restrict__ out) {
  int p = blockIdx.x * 256 + threadIdx.x;  // 131072
  float lim = (float)imgsz[0];
  float zn[64];
  {
    const uint4* zp4 = (const uint4*)(zt + (size_t)p * 64);
#pragma unroll
    for (int i = 0; i < 8; ++i) {
      uint4 v = zp4[i];
      unsigned a0 = v.x, a1 = v.y, a2 = v.z, a3 = v.w;
      zn[i * 8 + 0] = bf2f((unsigned short)(a0 & 0xffff));
      zn[i * 8 + 1] = bf2f((unsigned short)(a0 >> 16));
      zn[i * 8 + 2] = bf2f((unsigned short)(a1 & 0xffff));
      zn[i * 8 + 3] = bf2f((unsigned short)(a1 >> 16));
      zn[i * 8 + 4] = bf2f((unsigned short)(a2 & 0xffff));
      zn[i * 8 + 5] = bf2f((unsigned short)(a2 >> 16));
      zn[i * 8 + 6] = bf2f((unsigned short)(a3 & 0xffff));
      zn[i * 8 + 7] = bf2f((unsigned short)(a3 >> 16));
    }
#pragma unroll
    for (int i = 0; i < 54; ++i) zn[i] = zn[i] * zsc[i] + zsh[i];
  }
  int rem = p & 16383, h = rem >> 7, w = rem & 127;
  float fx = 16.f * (float)w, fy = 16.f * (float)h;
  size_t kbase = (size_t)p * 9;
  float* fgout = out;
  float* tsout = out + FGCNT;
  float* roout = out + FGCNT + TSCNT;
#pragma unroll
  for (int a = 0; a < 9; ++a) {
    float x1 = 20.f - 0.5f * AW[a] + fx;
    float y1 = 20.f - 0.5f * AH[a] + fy;
    float x2 = 19.f + 0.5f * AW[a] + fx;
    float y2 = 19.f + 0.5f * AH[a] + fy;
    float cx1 = fminf(fmaxf(x1 + zn[4 * a + 0], 0.f), lim);
    float cy1 = fminf(fmaxf(y1 + zn[4 * a + 1], 0.f), lim);
    float cx2 = fminf(fmaxf(x2 + zn[4 * a + 2], 0.f), lim);
    float cy2 = fminf(fmaxf(y2 + zn[4 * a + 3], 0.f), lim);
    float bw = cx2 - cx1, bh = cy2 - cy1;
    float cx = cx1 + 0.5f * bw, cy = cy1 + 0.5f * bh;
    float aw = AW[a] - 1.f, ah = AH[a] - 1.f;
    float acx = 19.5f + fx, acy = 19.5f + fy;
    float tx = (cx - acx) / aw, ty = (cy - acy) / ah;
    float tw = logf(fmaxf(bw / aw, 1e-30f));
    float th = logf(fmaxf(bh / ah, 1e-30f));
    float s0 = zn[36 + 2 * a], s1 = zn[36 + 2 * a + 1];
    float fg = 1.f / (1.f + expf(s0 - s1));
    fgout[kbase + a] = fg;
    size_t o4 = (kbase + a) * 4;
    tsout[o4 + 0] = tx; tsout[o4 + 1] = ty; tsout[o4 + 2] = tw; tsout[o4 + 3] = th;
    roout[o4 + 0] = cx; roout[o4 + 1] = cy; roout[o4 + 2] = bw; roout[o4 + 3] = bh;
  }
}

// ---------------- launch ----------------
extern "C" void kernel_launch(void* const* d_in, const int* in_sizes, int n_in,
                              void* d_out, int out_size, void* d_ws, size_t ws_size,
                              hipStream_t stream) {
  const float* x   = (const float*)d_in[0];
  const float* Wb  = (const float*)d_in[1];
  const float* bb  = (const float*)d_in[2];
  const float* gb  = (const float*)d_in[3];
  const float* beb = (const float*)d_in[4];
  const float* Wc  = (const float*)d_in[5];
  const float* bc  = (const float*)d_in[6];
  const float* gc  = (const float*)d_in[7];
  const float* bec = (const float*)d_in[8];
  const float* Wr  = (const float*)d_in[9];
  const float* br  = (const float*)d_in[10];
  const float* gr  = (const float*)d_in[11];
  const float* ber = (const float*)d_in[12];
  const int* imgsz = (const int*)d_in[13];

  char* ws = (char*)d_ws;
  const size_t OFF_XTP = 0;                        // 64*130*130*32*2 = 69,222,400
  const size_t OFF_Y   = 69222400;                 // 8*131072*32*2   = 67,108,864
  const size_t OFF_Z   = 136331264;                // 131072*64*2     = 16,777,216
  const size_t OFF_WT  = 153108480;                // 72*256*32*2     =  1,179,648
  const size_t OFF_W2  = 154288128;                // 8*64*32*2       =     32,768
  const size_t OFF_S   = 154320896;                // small area
  unsigned short* xt2  = (unsigned short*)(ws + OFF_XTP);
  unsigned short* yt2  = (unsigned short*)(ws + OFF_Y);
  unsigned short* zt   = (unsigned short*)(ws + OFF_Z);
  unsigned short* Wt2  = (unsigned short*)(ws + OFF_WT);
  unsigned short* W2t2 = (unsigned short*)(ws + OFF_W2);
  float* b2     = (float*)(ws + OFF_S);            // 64 f
  float* statsA = (float*)(ws + OFF_S + 256);      // 512 f
  float* statsZ = (float*)(ws + OFF_S + 2304);     // 128 f
  float* zsc    = (float*)(ws + OFF_S + 2816);     // 64 f
  float* zsh    = (float*)(ws + OFF_S + 3072);     // 64 f
  float* out = (float*)d_out;

  hipMemsetAsync(statsA, 0, (512 + 128) * sizeof(float), stream);
  k_wt  <<<2304, 256, 0, stream>>>(Wb, Wt2);
  k_tr  <<<8192, 256, 0, stream>>>(x, xt2);
  k_bord<<<516, 256, 0, stream>>>(xt2);
  k_conv<<<2048, 256, 0, stream>>>(xt2, Wt2, bb, yt2, statsA);
  k_fold<<<1, 256, 0, stream>>>(statsA, gb, beb, Wc, bc, Wr, br, W2t2, b2);
  k_mm2 <<<1024, 256, 0, stream>>>(yt2, W2t2, b2, zt, statsZ);
  k_zstat<<<1, 64, 0, stream>>>(statsZ, gc, bec, gr, ber, zsc, zsh);
  k_dec <<<512, 256, 0, stream>>>(zt, zsc, zsh, imgsz, out);
}

// Round 12
// 554.360 us; speedup vs baseline: 1.0727x; 1.0727x over previous
//
#include <hip/hip_runtime.h>
#include <stdint.h>

// ---------------- types / helpers ----------------
typedef short bf16x8 __attribute__((ext_vector_type(8)));
typedef float f32x4 __attribute__((ext_vector_type(4)));

#define AS1 __attribute__((address_space(1)))
#define AS3 __attribute__((address_space(3)))

static __device__ __forceinline__ void gl16(const void* g, void* l) {
  __builtin_amdgcn_global_load_lds((const AS1 void*)g, (AS3 void*)l, 16, 0, 0);
}

static __device__ __forceinline__ unsigned short f2bf(float f) {
  unsigned u = __float_as_uint(f);
  u = u + 0x7fffu + ((u >> 16) & 1u);
  return (unsigned short)(u >> 16);
}
static __device__ __forceinline__ float bf2f(unsigned short h) {
  return __uint_as_float(((unsigned)h) << 16);
}
static __device__ __forceinline__ float mishf(float x) {
  float sp = fmaxf(x, 0.f) + log1pf(expf(-fabsf(x)));
  float e2 = expf(-2.f * sp);
  float th = (1.f - e2) / (1.f + e2);
  return x * th;
}

// geometry
#define NIMG 8
#define HH 128
#define WW 128
#define HP 130
#define CIN 256
#define MPIX (NIMG * HH * WW)       // 131072
#define KTOT 2304                   // 72 slices of 32
#define FGCNT (MPIX * 9)            // 1179648
#define TSCNT (MPIX * 9 * 4)        // 4718592

__device__ __constant__ float AW[9] = {456.f, 912.f, 1824.f, 320.f, 640.f, 1280.f, 224.f, 448.f, 896.f};
__device__ __constant__ float AH[9] = {224.f, 448.f, 896.f, 320.f, 640.f, 1280.f, 448.f, 896.f, 1792.f};

// ---------------- K0a: conv weights -> Wt2[slice][oc][32] bf16, slice = icb*9 + kh*3 + kw ----------------
__global__ __launch_bounds__(256) void k_wt(const float* __restrict__ Wb,
                                            unsigned short* __restrict__ Wt2) {
  int d = blockIdx.x * 256 + threadIdx.x;  // 589824 = 72*256*32
  int c = d & 31, oc = (d >> 5) & 255, s = d >> 13;
  int icb = s / 9, khw = s % 9, kh = khw / 3, kw = khw % 3;
  int ic = icb * 32 + c;
  Wt2[d] = f2bf(Wb[((oc * 256 + ic) * 3 + kh) * 3 + kw]);
}

// ---------------- K0b: x (NCHW f32) -> xt2 (channel-blocked padded) interior ----------------
// xt2 layout: [icb(8)*8+n][130][130][32] bf16
__global__ __launch_bounds__(256) void k_tr(const float* __restrict__ x,
                                            unsigned short* __restrict__ xt2) {
  __shared__ float tile[32][129];
  int b = blockIdx.x;  // 8 n * 128 h * 8 icb = 8192
  int icb = b & 7, h = (b >> 3) & 127, n = b >> 10;
  int t = threadIdx.x;
  const float* src = x + (((size_t)(n * 256 + icb * 32) * 128 + h) * 128);
#pragma unroll
  for (int i = 0; i < 4; ++i) {
    int idx = t + 256 * i;          // 1024 float4 units
    int w4 = idx & 31, ic = idx >> 5;
    float4 v = *(const float4*)(src + (size_t)ic * 16384 + w4 * 4);
    tile[ic][w4 * 4 + 0] = v.x; tile[ic][w4 * 4 + 1] = v.y;
    tile[ic][w4 * 4 + 2] = v.z; tile[ic][w4 * 4 + 3] = v.w;
  }
  __syncthreads();
#pragma unroll
  for (int i = 0; i < 8; ++i) {
    int idx = t + 256 * i;          // 2048 bf16-pairs
    int icp = idx & 15, w = idx >> 4;
    unsigned lo = f2bf(tile[icp * 2][w]);
    unsigned hi = f2bf(tile[icp * 2 + 1][w]);
    size_t pix = ((size_t)(icb * 8 + n) * HP + (h + 1)) * HP + (w + 1);
    *(unsigned*)(xt2 + pix * 32 + icp * 2) = lo | (hi << 16);
  }
}

// ---------------- K0c: zero padded borders of xt2 ----------------
__global__ __launch_bounds__(256) void k_bord(unsigned short* __restrict__ xt2) {
  int tid = blockIdx.x * 256 + threadIdx.x;  // 64 planes * 516 border pix * 4 chunks = 132096
  int chunk = tid & 3, pix = tid >> 2;
  int nn = pix / 516, bp = pix % 516;        // nn = icb*8+n plane
  int hp, wp;
  if (bp < 130) { hp = 0; wp = bp; }
  else if (bp < 260) { hp = 129; wp = bp - 130; }
  else { int r = bp - 260; hp = 1 + (r >> 1); wp = (r & 1) ? 129 : 0; }
  size_t off = (((size_t)nn * HP + hp) * HP + wp) * 32 + chunk * 8;
  uint4 z = {0u, 0u, 0u, 0u};
  *(uint4*)(xt2 + off) = z;
}

// ---------------- K1: conv3x3 implicit GEMM — kw-in-LDS macro-steps ----------------
// R11 lesson: stage-drain time scales with BYTES staged per barrier (~4 B/cyc/CU
// effective), so cut bytes/MFMA. The 3 kw taps share one A row: stage it ONCE.
// Macro-step = (icb, kh), 24 total: stage A row (9 regions = 144 px, 9KB) +
// 3 B slices (24 regions, 24KB); inside one barrier pair run 3 kw sub-steps,
// reading A frags at pixel offset +kw (region-major addr handles the wrap; the
// 16-lane offset set is the same rotated -> same 0-conflict pattern, R8-proven).
// Per block: A staging 576->216KB, barriers 72->24, 48 MFMA/wave per barrier.
// Single 33.75KB buffer, plain __syncthreads (m141 lesson), 4 waves, acc[4][4],
// ~3 blocks/CU co-resident.
__global__ __launch_bounds__(256) void k_conv(const unsigned short* __restrict__ xt2,
                                              const unsigned short* __restrict__ Wt2,
                                              const float* __restrict__ b_base,
                                              unsigned short* __restrict__ yt2,
                                              float* __restrict__ statsA) {
  __shared__ __align__(16) char lds[33792];    // A 9*1024 | B 24*1024
  char* ldsA = lds;
  char* ldsB = lds + 9216;
  int t = threadIdx.x;
  int lane = t & 63, w4 = t >> 6;              // 4 waves
  int wr = w4 >> 1, wc = w4 & 1;               // 2M x 2N wave grid, wave tile 64x64
  int row16 = lane & 15, kgl = lane >> 4;
  int pr = lane & 15, pq = lane >> 4;          // staging lane decomposition

  int bid = blockIdx.x;                        // 2048, %8==0 -> bijective
  int swz = (bid & 7) * 256 + (bid >> 3);      // XCD k owns contiguous 256 tiles
  int pixb = swz >> 1, oh = swz & 1;
  int n = pixb >> 7, h0 = pixb & 127;
  size_t M0 = (size_t)pixb * 128;

  f32x4 acc[4][4];
#pragma unroll
  for (int m = 0; m < 4; ++m)
#pragma unroll
    for (int nf = 0; nf < 4; ++nf) { f32x4 z = {0.f, 0.f, 0.f, 0.f}; acc[m][nf] = z; }

  const size_t planeStride = (size_t)HP * HP * 32;   // one plane, in shorts
  int laneOffA = pr * 32 + pq * 8;                   // within-region src offset

  for (int icb = 0; icb < 8; ++icb) {
    for (int kh = 0; kh < 3; ++kh) {
      // A row: plane icb*8+n, padded row h0+kh, pixels 0..143 (130 valid)
      const unsigned short* aRow =
          xt2 + (size_t)((icb * 8 + n) * HP + h0 + kh) * HP * 32;
      gl16(aRow + w4 * 512 + laneOffA, ldsA + w4 * 1024);
      gl16(aRow + (w4 + 4) * 512 + laneOffA, ldsA + (w4 + 4) * 1024);
      if (w4 == 0) gl16(aRow + 8 * 512 + laneOffA, ldsA + 8 * 1024);
      // B: 3 slices (kw 0..2) x 8 regions; wave w4 stages g = w4 + 4j
      int slb = icb * 9 + kh * 3;
#pragma unroll
      for (int j = 0; j < 6; ++j) {
        int g = w4 + 4 * j;                    // 0..23
        int kw_ = g >> 3, gg = g & 7;
        gl16(Wt2 + ((size_t)(slb + kw_) * 256 + oh * 128 + gg * 16 + pr) * 32 + pq * 8,
             ldsB + g * 1024);
      }
      __syncthreads();
#pragma unroll
      for (int kw = 0; kw < 3; ++kw) {
        bf16x8 af[4], bfr[4];
#pragma unroll
        for (int m = 0; m < 4; ++m) {
          int p = wr * 64 + m * 16 + row16 + kw;
          af[m] = *(const bf16x8*)(ldsA + (p >> 4) * 1024 + kgl * 256 + (p & 15) * 16);
        }
#pragma unroll
        for (int nf = 0; nf < 4; ++nf)
          bfr[nf] = *(const bf16x8*)(ldsB + (kw * 8 + wc * 4 + nf) * 1024 + kgl * 256 + row16 * 16);
#pragma unroll
        for (int m = 0; m < 4; ++m)
#pragma unroll
          for (int nf = 0; nf < 4; ++nf)
            acc[m][nf] = __builtin_amdgcn_mfma_f32_16x16x32_bf16(af[m], bfr[nf], acc[m][nf], 0, 0, 0);
      }
      __syncthreads();
    }
  }

  // epilogue: bias + mish, store channel-blocked yt2[oc>>5][pix][oc&31], stats
  float sums[4] = {0.f, 0.f, 0.f, 0.f}, sumq[4] = {0.f, 0.f, 0.f, 0.f};
#pragma unroll
  for (int nf = 0; nf < 4; ++nf) {
    int oc = oh * 128 + wc * 64 + nf * 16 + row16;
    float bias = b_base[oc];
    size_t obase = (size_t)(oc >> 5) * MPIX * 32 + (oc & 31);
#pragma unroll
    for (int m = 0; m < 4; ++m) {
#pragma unroll
      for (int j = 0; j < 4; ++j) {
        int p = wr * 64 + m * 16 + kgl * 4 + j;
        float y = mishf(acc[m][nf][j] + bias);
        yt2[obase + (M0 + p) * 32] = f2bf(y);
        sums[nf] += y; sumq[nf] += y * y;
      }
    }
  }
#pragma unroll
  for (int nf = 0; nf < 4; ++nf) {
    float s1 = sums[nf], s2 = sumq[nf];
    s1 += __shfl_xor(s1, 16); s2 += __shfl_xor(s2, 16);
    s1 += __shfl_xor(s1, 32); s2 += __shfl_xor(s2, 32);
    if (lane < 16) {
      int oc = oh * 128 + wc * 64 + nf * 16 + lane;
      atomicAdd(&statsA[oc], s1);
      atomicAdd(&statsA[256 + oc], s2);
    }
  }
}

// ---------------- K2: finalize base BN, fold into fused 1x1 weights ----------------
// W2t2 layout: [s(8)][64 oc][32] bf16
__global__ __launch_bounds__(256) void k_fold(const float* __restrict__ statsA,
                                              const float* __restrict__ g_base,
                                              const float* __restrict__ be_base,
                                              const float* __restrict__ W_cls,
                                              const float* __restrict__ b_cls,
                                              const float* __restrict__ W_reg,
                                              const float* __restrict__ b_reg,
                                              unsigned short* __restrict__ W2t2,
                                              float* __restrict__ b2) {
  __shared__ float sS[256], sT[256];
  int t = threadIdx.x;
  {
    float cnt = (float)MPIX;
    float m = statsA[t] / cnt;
    float v = fmaxf(statsA[256 + t] / cnt - m * m, 0.f);
    float s = g_base[t] * rsqrtf(v + 1e-5f);
    sS[t] = s;
    sT[t] = be_base[t] - m * s;
  }
  __syncthreads();
  if (t < 64) {
    float bias = 0.f;
    if (t < 36) bias = b_reg[t];
    else if (t < 54) bias = b_cls[t - 36];
    float acc = 0.f;
    for (int ic = 0; ic < 256; ++ic) {
      float w = 0.f;
      if (t < 36) w = W_reg[t * 256 + ic];
      else if (t < 54) w = W_cls[(t - 36) * 256 + ic];
      acc += w * sT[ic];
      W2t2[((size_t)(ic >> 5) * 64 + t) * 32 + (ic & 31)] = f2bf(w * sS[ic]);
    }
    b2[t] = bias + acc;
  }
}

// ---------------- K3: fused 1x1 heads GEMM (M=131072, N=64, K=256) + z stats ----------------
// Region-major LDS + 2-phase dbuf. 4 waves, 24KB LDS.
__global__ __launch_bounds__(256) void k_mm2(const unsigned short* __restrict__ yt2,
                                             const unsigned short* __restrict__ W2t2,
                                             const float* __restrict__ b2,
                                             unsigned short* __restrict__ zt,
                                             float* __restrict__ statsZ) {
  __shared__ __align__(16) char lds2[24576];   // 2 x (A 8KB | B 4KB)
  int t = threadIdx.x, lane = t & 63, w4 = t >> 6;   // 4 waves
  int row16 = lane & 15, kgl = lane >> 4;
  int pr = lane & 15, pq = lane >> 4;
  size_t pixbase = (size_t)blockIdx.x * 128;

  f32x4 acc[2][4];
#pragma unroll
  for (int m = 0; m < 2; ++m)
#pragma unroll
    for (int nn = 0; nn < 4; ++nn) { f32x4 z = {0.f, 0.f, 0.f, 0.f}; acc[m][nn] = z; }

  // A: wave w4 stages regions 2w4, 2w4+1 (pixels 32w4 .. +31)
  const unsigned short* aS0 = yt2 + (pixbase + w4 * 32 + pr) * 32 + pq * 8;
  const unsigned short* aS1 = aS0 + 16 * 32;
  // B: wave w4 stages region w4 (ocs 16w4 .. +15)
  const unsigned short* bS = W2t2 + (size_t)(w4 * 16 + pr) * 32 + pq * 8;

  int aoffA = w4 * 2048 + kgl * 256 + row16 * 16;  // + m*1024
  int aoffB = kgl * 256 + row16 * 16;              // + nn*1024

  auto STG = [&](int s, int c_) {
    size_t ao = (size_t)s * MPIX * 32;
    size_t bo = (size_t)s * 2048;          // 64 oc * 32
    char* buf = lds2 + c_ * 12288;
    gl16(aS0 + ao, buf + (2 * w4) * 1024);
    gl16(aS1 + ao, buf + (2 * w4 + 1) * 1024);
    gl16(bS + bo, buf + 8192 + w4 * 1024);
  };

  STG(0, 0);
  int cur = 0;
  for (int s = 0; s < 8; ++s) {
    __syncthreads();
    if (s < 7) STG(s + 1, cur ^ 1);
    const char* ab = lds2 + cur * 12288;
    const char* bb = ab + 8192;
    bf16x8 af[2], bfr[4];
#pragma unroll
    for (int m = 0; m < 2; ++m) af[m] = *(const bf16x8*)(ab + aoffA + m * 1024);
#pragma unroll
    for (int nn = 0; nn < 4; ++nn) bfr[nn] = *(const bf16x8*)(bb + aoffB + nn * 1024);
#pragma unroll
    for (int m = 0; m < 2; ++m)
#pragma unroll
      for (int nn = 0; nn < 4; ++nn)
        acc[m][nn] = __builtin_amdgcn_mfma_f32_16x16x32_bf16(af[m], bfr[nn], acc[m][nn], 0, 0, 0);
    cur ^= 1;
  }

  float sums[4] = {0.f, 0.f, 0.f, 0.f}, sumq[4] = {0.f, 0.f, 0.f, 0.f};
#pragma unroll
  for (int nn = 0; nn < 4; ++nn) {
    int oc = nn * 16 + row16;
    float bias = b2[oc];
#pragma unroll
    for (int m = 0; m < 2; ++m) {
#pragma unroll
      for (int j = 0; j < 4; ++j) {
        int p = w4 * 32 + m * 16 + kgl * 4 + j;
        float v = acc[m][nn][j] + bias;
        zt[(pixbase + p) * 64 + oc] = f2bf(v);
        sums[nn] += v; sumq[nn] += v * v;
      }
    }
  }
#pragma unroll
  for (int nn = 0; nn < 4; ++nn) {
    float s1 = sums[nn], s2 = sumq[nn];
    s1 += __shfl_xor(s1, 16); s2 += __shfl_xor(s2, 16);
    s1 += __shfl_xor(s1, 32); s2 += __shfl_xor(s2, 32);
    if (lane < 16) {
      int oc = nn * 16 + lane;
      atomicAdd(&statsZ[oc], s1);
      atomicAdd(&statsZ[64 + oc], s2);
    }
  }
}

// ---------------- K4: finalize z BN scale/shift ----------------
__global__ __launch_bounds__(64) void k_zstat(const float* __restrict__ statsZ,
                                              const float* __restrict__ g_cls,
                                              const float* __restrict__ be_cls,
                                              const float* __restrict__ g_reg,
                                              const float* __restrict__ be_reg,
                                              float* __restrict__ zsc,
                                              float* __restrict__ zsh) {
  int t = threadIdx.x;  // 64
  float g = 1.f, be = 0.f;
  if (t < 36) { g = g_reg[t]; be = be_reg[t]; }
  else if (t < 54) { g = g_cls[t - 36]; be = be_cls[t - 36]; }
  float cnt = (float)MPIX;
  float m = statsZ[t] / cnt;
  float v = fmaxf(statsZ[64 + t] / cnt - m * m, 0.f);
  float s = g * rsqrtf(v + 1e-5f);
  zsc[t] = s;
  zsh[t] = be - m * s;
}

// ---------------- K5: BN-apply + softmax + anchor decode + outputs ----------------
__global__ __launch_bounds__(256) void k_dec(const unsigned short* __restrict__ zt,
                                             const float* __restrict__ zsc,
                                             const float* __restrict__ zsh,
                                             const int* __restrict__ imgsz,
                                             float* __restrict__ out) {
  int p = blockIdx.x * 256 + threadIdx.x;  // 131072
  float lim = (float)imgsz[0];
  float zn[64];
  {
    const uint4* zp4 = (const uint4*)(zt + (size_t)p * 64);
#pragma unroll
    for (int i = 0; i < 8; ++i) {
      uint4 v = zp4[i];
      unsigned a0 = v.x, a1 = v.y, a2 = v.z, a3 = v.w;
      zn[i * 8 + 0] = bf2f((unsigned short)(a0 & 0xffff));
      zn[i * 8 + 1] = bf2f((unsigned short)(a0 >> 16));
      zn[i * 8 + 2] = bf2f((unsigned short)(a1 & 0xffff));
      zn[i * 8 + 3] = bf2f((unsigned short)(a1 >> 16));
      zn[i * 8 + 4] = bf2f((unsigned short)(a2 & 0xffff));
      zn[i * 8 + 5] = bf2f((unsigned short)(a2 >> 16));
      zn[i * 8 + 6] = bf2f((unsigned short)(a3 & 0xffff));
      zn[i * 8 + 7] = bf2f((unsigned short)(a3 >> 16));
    }
#pragma unroll
    for (int i = 0; i < 54; ++i) zn[i] = zn[i] * zsc[i] + zsh[i];
  }
  int rem = p & 16383, h = rem >> 7, w = rem & 127;
  float fx = 16.f * (float)w, fy = 16.f * (float)h;
  size_t kbase = (size_t)p * 9;
  float* fgout = out;
  float* tsout = out + FGCNT;
  float* roout = out + FGCNT + TSCNT;
#pragma unroll
  for (int a = 0; a < 9; ++a) {
    float x1 = 20.f - 0.5f * AW[a] + fx;
    float y1 = 20.f - 0.5f * AH[a] + fy;
    float x2 = 19.f + 0.5f * AW[a] + fx;
    float y2 = 19.f + 0.5f * AH[a] + fy;
    float cx1 = fminf(fmaxf(x1 + zn[4 * a + 0], 0.f), lim);
    float cy1 = fminf(fmaxf(y1 + zn[4 * a + 1], 0.f), lim);
    float cx2 = fminf(fmaxf(x2 + zn[4 * a + 2], 0.f), lim);
    float cy2 = fminf(fmaxf(y2 + zn[4 * a + 3], 0.f), lim);
    float bw = cx2 - cx1, bh = cy2 - cy1;
    float cx = cx1 + 0.5f * bw, cy = cy1 + 0.5f * bh;
    float aw = AW[a] - 1.f, ah = AH[a] - 1.f;
    float acx = 19.5f + fx, acy = 19.5f + fy;
    float tx = (cx - acx) / aw, ty = (cy - acy) / ah;
    float tw = logf(fmaxf(bw / aw, 1e-30f));
    float th = logf(fmaxf(bh / ah, 1e-30f));
    float s0 = zn[36 + 2 * a], s1 = zn[36 + 2 * a + 1];
    float fg = 1.f / (1.f + expf(s0 - s1));
    fgout[kbase + a] = fg;
    size_t o4 = (kbase + a) * 4;
    tsout[o4 + 0] = tx; tsout[o4 + 1] = ty; tsout[o4 + 2] = tw; tsout[o4 + 3] = th;
    roout[o4 + 0] = cx; roout[o4 + 1] = cy; roout[o4 + 2] = bw; roout[o4 + 3] = bh;
  }
}

// ---------------- launch ----------------
extern "C" void kernel_launch(void* const* d_in, const int* in_sizes, int n_in,
                              void* d_out, int out_size, void* d_ws, size_t ws_size,
                              hipStream_t stream) {
  const float* x   = (const float*)d_in[0];
  const float* Wb  = (const float*)d_in[1];
  const float* bb  = (const float*)d_in[2];
  const float* gb  = (const float*)d_in[3];
  const float* beb = (const float*)d_in[4];
  const float* Wc  = (const float*)d_in[5];
  const float* bc  = (const float*)d_in[6];
  const float* gc  = (const float*)d_in[7];
  const float* bec = (const float*)d_in[8];
  const float* Wr  = (const float*)d_in[9];
  const float* br  = (const float*)d_in[10];
  const float* gr  = (const float*)d_in[11];
  const float* ber = (const float*)d_in[12];
  const int* imgsz = (const int*)d_in[13];

  char* ws = (char*)d_ws;
  const size_t OFF_XTP = 0;                        // 64*130*130*32*2 = 69,222,400
  const size_t OFF_Y   = 69222400;                 // 8*131072*32*2   = 67,108,864
  const size_t OFF_Z   = 136331264;                // 131072*64*2     = 16,777,216
  const size_t OFF_WT  = 153108480;                // 72*256*32*2     =  1,179,648
  const size_t OFF_W2  = 154288128;                // 8*64*32*2       =     32,768
  const size_t OFF_S   = 154320896;                // small area
  unsigned short* xt2  = (unsigned short*)(ws + OFF_XTP);
  unsigned short* yt2  = (unsigned short*)(ws + OFF_Y);
  unsigned short* zt   = (unsigned short*)(ws + OFF_Z);
  unsigned short* Wt2  = (unsigned short*)(ws + OFF_WT);
  unsigned short* W2t2 = (unsigned short*)(ws + OFF_W2);
  float* b2     = (float*)(ws + OFF_S);            // 64 f
  float* statsA = (float*)(ws + OFF_S + 256);      // 512 f
  float* statsZ = (float*)(ws + OFF_S + 2304);     // 128 f
  float* zsc    = (float*)(ws + OFF_S + 2816);     // 64 f
  float* zsh    = (float*)(ws + OFF_S + 3072);     // 64 f
  float* out = (float*)d_out;

  hipMemsetAsync(statsA, 0, (512 + 128) * sizeof(float), stream);
  k_wt  <<<2304, 256, 0, stream>>>(Wb, Wt2);
  k_tr  <<<8192, 256, 0, stream>>>(x, xt2);
  k_bord<<<516, 256, 0, stream>>>(xt2);
  k_conv<<<2048, 256, 0, stream>>>(xt2, Wt2, bb, yt2, statsA);
  k_fold<<<1, 256, 0, stream>>>(statsA, gb, beb, Wc, bc, Wr, br, W2t2, b2);
  k_mm2 <<<1024, 256, 0, stream>>>(yt2, W2t2, b2, zt, statsZ);
  k_zstat<<<1, 64, 0, stream>>>(statsZ, gc, bec, gr, ber, zsc, zsh);
  k_dec <<<512, 256, 0, stream>>>(zt, zsc, zsh, imgsz, out);
}

// Round 13
// 502.043 us; speedup vs baseline: 1.1845x; 1.1042x over previous
//
#include <hip/hip_runtime.h>
#include <stdint.h>

// ---------------- types / helpers ----------------
typedef short bf16x8 __attribute__((ext_vector_type(8)));
typedef float f32x4 __attribute__((ext_vector_type(4)));

#define AS1 __attribute__((address_space(1)))
#define AS3 __attribute__((address_space(3)))

static __device__ __forceinline__ void gl16(const void* g, void* l) {
  __builtin_amdgcn_global_load_lds((const AS1 void*)g, (AS3 void*)l, 16, 0, 0);
}

static __device__ __forceinline__ unsigned short f2bf(float f) {
  unsigned u = __float_as_uint(f);
  u = u + 0x7fffu + ((u >> 16) & 1u);
  return (unsigned short)(u >> 16);
}
static __device__ __forceinline__ float bf2f(unsigned short h) {
  return __uint_as_float(((unsigned)h) << 16);
}
static __device__ __forceinline__ float mishf(float x) {
  float sp = fmaxf(x, 0.f) + log1pf(expf(-fabsf(x)));
  float e2 = expf(-2.f * sp);
  float th = (1.f - e2) / (1.f + e2);
  return x * th;
}

// geometry
#define NIMG 8
#define HH 128
#define WW 128
#define HP 130
#define CIN 256
#define MPIX (NIMG * HH * WW)       // 131072
#define KTOT 2304                   // 72 slices of 32
#define FGCNT (MPIX * 9)            // 1179648
#define TSCNT (MPIX * 9 * 4)        // 4718592

__device__ __constant__ float AW[9] = {456.f, 912.f, 1824.f, 320.f, 640.f, 1280.f, 224.f, 448.f, 896.f};
__device__ __constant__ float AH[9] = {224.f, 448.f, 896.f, 320.f, 640.f, 1280.f, 448.f, 896.f, 1792.f};

// ---------------- K0a: conv weights -> Wt2[slice][oc][32] bf16, slice = icb*9 + kh*3 + kw ----------------
__global__ __launch_bounds__(256) void k_wt(const float* __restrict__ Wb,
                                            unsigned short* __restrict__ Wt2) {
  int d = blockIdx.x * 256 + threadIdx.x;  // 589824 = 72*256*32
  int c = d & 31, oc = (d >> 5) & 255, s = d >> 13;
  int icb = s / 9, khw = s % 9, kh = khw / 3, kw = khw % 3;
  int ic = icb * 32 + c;
  Wt2[d] = f2bf(Wb[((oc * 256 + ic) * 3 + kh) * 3 + kw]);
}

// ---------------- K0b: x (NCHW f32) -> xt2 (channel-blocked padded) interior ----------------
// xt2 layout: [icb(8)*8+n][130][130][32] bf16
__global__ __launch_bounds__(256) void k_tr(const float* __restrict__ x,
                                            unsigned short* __restrict__ xt2) {
  __shared__ float tile[32][129];
  int b = blockIdx.x;  // 8 n * 128 h * 8 icb = 8192
  int icb = b & 7, h = (b >> 3) & 127, n = b >> 10;
  int t = threadIdx.x;
  const float* src = x + (((size_t)(n * 256 + icb * 32) * 128 + h) * 128);
#pragma unroll
  for (int i = 0; i < 4; ++i) {
    int idx = t + 256 * i;          // 1024 float4 units
    int w4 = idx & 31, ic = idx >> 5;
    float4 v = *(const float4*)(src + (size_t)ic * 16384 + w4 * 4);
    tile[ic][w4 * 4 + 0] = v.x; tile[ic][w4 * 4 + 1] = v.y;
    tile[ic][w4 * 4 + 2] = v.z; tile[ic][w4 * 4 + 3] = v.w;
  }
  __syncthreads();
#pragma unroll
  for (int i = 0; i < 8; ++i) {
    int idx = t + 256 * i;          // 2048 bf16-pairs
    int icp = idx & 15, w = idx >> 4;
    unsigned lo = f2bf(tile[icp * 2][w]);
    unsigned hi = f2bf(tile[icp * 2 + 1][w]);
    size_t pix = ((size_t)(icb * 8 + n) * HP + (h + 1)) * HP + (w + 1);
    *(unsigned*)(xt2 + pix * 32 + icp * 2) = lo | (hi << 16);
  }
}

// ---------------- K0c: zero padded borders of xt2 ----------------
__global__ __launch_bounds__(256) void k_bord(unsigned short* __restrict__ xt2) {
  int tid = blockIdx.x * 256 + threadIdx.x;  // 64 planes * 516 border pix * 4 chunks = 132096
  int chunk = tid & 3, pix = tid >> 2;
  int nn = pix / 516, bp = pix % 516;        // nn = icb*8+n plane
  int hp, wp;
  if (bp < 130) { hp = 0; wp = bp; }
  else if (bp < 260) { hp = 129; wp = bp - 130; }
  else { int r = bp - 260; hp = 1 + (r >> 1); wp = (r & 1) ? 129 : 0; }
  size_t off = (((size_t)nn * HP + hp) * HP + wp) * 32 + chunk * 8;
  uint4 z = {0u, 0u, 0u, 0u};
  *(uint4*)(xt2 + off) = z;
}

// ---------------- K1: conv3x3 implicit GEMM — R10 config (best measured: 372us) ----------------
// Six schedule/structure variants (R5/R8-R12) all pin at 372-437us, MfmaUtil
// ~18%: structural plateau for M=131072/N=256/K=2304 at this tile family.
// Counted-vmcnt depth-2, 3 x 16KB buffers, region-major LDS (0-conflict),
// icb-major K order, bijective XCD swizzle. Kept verbatim from R10.
__global__ __launch_bounds__(256) void k_conv(const unsigned short* __restrict__ xt2,
                                              const unsigned short* __restrict__ Wt2,
                                              const float* __restrict__ b_base,
                                              unsigned short* __restrict__ yt2,
                                              float* __restrict__ statsA) {
  __shared__ __align__(16) char lds[49152];    // 3 x (A 8KB | B 8KB)
  int t = threadIdx.x;
  int lane = t & 63, w4 = t >> 6;              // 4 waves
  int wr = w4 >> 1, wc = w4 & 1;               // 2M x 2N wave grid, wave tile 64x64
  int row16 = lane & 15, kgl = lane >> 4;
  int pr = lane & 15, pq = lane >> 4;          // staging lane decomposition

  int bid = blockIdx.x;                        // 2048, %8==0 -> bijective
  int swz = (bid & 7) * 256 + (bid >> 3);      // XCD k owns contiguous 256 tiles
  int pixb = swz >> 1, oh = swz & 1;
  int n = pixb >> 7, h0 = pixb & 127;
  size_t M0 = (size_t)pixb * 128;

  f32x4 acc[4][4];
#pragma unroll
  for (int m = 0; m < 4; ++m)
#pragma unroll
    for (int nf = 0; nf < 4; ++nf) { f32x4 z = {0.f, 0.f, 0.f, 0.f}; acc[m][nf] = z; }

  // A: wave w4 stages regions 2w4, 2w4+1 (pixels 32w4 .. +31)
  const unsigned short* aS0 =
      xt2 + ((size_t)(n * HP + h0) * HP + w4 * 32 + pr) * 32 + pq * 8;
  const unsigned short* aS1 = aS0 + 16 * 32;
  // B: wave w4 stages regions 2w4, 2w4+1 (ocs oh*128 + 32w4 .. +31)
  const unsigned short* bS0 = Wt2 + (size_t)(oh * 128 + w4 * 32 + pr) * 32 + pq * 8;
  const unsigned short* bS1 = bS0 + 16 * 32;

  const size_t planeStride = (size_t)8 * HP * HP * 32;
  int aoffA = wr * 4096 + kgl * 256 + row16 * 16;   // + m*1024
  int aoffB = wc * 4096 + kgl * 256 + row16 * 16;   // + nf*1024

  auto STAGE = [&](int sv, int b_) {
    int icb_ = (sv * 57) >> 9;         // sv/9 for sv<512
    int khw = sv - icb_ * 9;
    int kh_ = (khw * 11) >> 5;         // khw/3 for khw<9
    int kw_ = khw - kh_ * 3;
    size_t offA = (size_t)icb_ * planeStride + ((size_t)kh_ * HP + kw_) * 32;
    size_t offB = (size_t)sv * 8192;   // 256 oc * 32 shorts per k-step
    char* buf = lds + b_ * 16384;
    gl16(aS0 + offA, buf + (2 * w4) * 1024);
    gl16(aS1 + offA, buf + (2 * w4 + 1) * 1024);
    gl16(bS0 + offB, buf + 8192 + (2 * w4) * 1024);
    gl16(bS1 + offB, buf + 8192 + (2 * w4 + 1) * 1024);
  };

  STAGE(0, 0);
  STAGE(1, 1);
  int cur = 0, nxt = 2;
  for (int s = 0; s < 72; ++s) {
    if (s < 71) { asm volatile("s_waitcnt vmcnt(4)" ::: "memory"); }
    else        { asm volatile("s_waitcnt vmcnt(0)" ::: "memory"); }
    __builtin_amdgcn_s_barrier();
    if (s < 70) STAGE(s + 2, nxt);
    const char* ab = lds + cur * 16384;
    const char* bb = ab + 8192;
    bf16x8 af[4], bfr[4];
#pragma unroll
    for (int m = 0; m < 4; ++m) af[m] = *(const bf16x8*)(ab + aoffA + m * 1024);
#pragma unroll
    for (int nf = 0; nf < 4; ++nf) bfr[nf] = *(const bf16x8*)(bb + aoffB + nf * 1024);
#pragma unroll
    for (int m = 0; m < 4; ++m)
#pragma unroll
      for (int nf = 0; nf < 4; ++nf)
        acc[m][nf] = __builtin_amdgcn_mfma_f32_16x16x32_bf16(af[m], bfr[nf], acc[m][nf], 0, 0, 0);
    cur = (cur == 2) ? 0 : cur + 1;
    nxt = (nxt == 2) ? 0 : nxt + 1;
  }

  // epilogue: bias + mish, store channel-blocked yt2[oc>>5][pix][oc&31], stats
  float sums[4] = {0.f, 0.f, 0.f, 0.f}, sumq[4] = {0.f, 0.f, 0.f, 0.f};
#pragma unroll
  for (int nf = 0; nf < 4; ++nf) {
    int oc = oh * 128 + wc * 64 + nf * 16 + row16;
    float bias = b_base[oc];
    size_t obase = (size_t)(oc >> 5) * MPIX * 32 + (oc & 31);
#pragma unroll
    for (int m = 0; m < 4; ++m) {
#pragma unroll
      for (int j = 0; j < 4; ++j) {
        int p = wr * 64 + m * 16 + kgl * 4 + j;
        float y = mishf(acc[m][nf][j] + bias);
        yt2[obase + (M0 + p) * 32] = f2bf(y);
        sums[nf] += y; sumq[nf] += y * y;
      }
    }
  }
#pragma unroll
  for (int nf = 0; nf < 4; ++nf) {
    float s1 = sums[nf], s2 = sumq[nf];
    s1 += __shfl_xor(s1, 16); s2 += __shfl_xor(s2, 16);
    s1 += __shfl_xor(s1, 32); s2 += __shfl_xor(s2, 32);
    if (lane < 16) {
      int oc = oh * 128 + wc * 64 + nf * 16 + lane;
      atomicAdd(&statsA[oc], s1);
      atomicAdd(&statsA[256 + oc], s2);
    }
  }
}

// ---------------- K2: finalize base BN, fold into fused 1x1 weights ----------------
// W2t2 layout: [icb(8)][64 oc][32] bf16. Phase 2 parallelized: (oc, ic-quarter)
// over all 256 threads + LDS reduce (was: 64 threads x 256 serial iters).
__global__ __launch_bounds__(256) void k_fold(const float* __restrict__ statsA,
                                              const float* __restrict__ g_base,
                                              const float* __restrict__ be_base,
                                              const float* __restrict__ W_cls,
                                              const float* __restrict__ b_cls,
                                              const float* __restrict__ W_reg,
                                              const float* __restrict__ b_reg,
                                              unsigned short* __restrict__ W2t2,
                                              float* __restrict__ b2) {
  __shared__ float sS[256], sT[256], sP[4][64];
  int t = threadIdx.x;
  {
    float cnt = (float)MPIX;
    float m = statsA[t] / cnt;
    float v = fmaxf(statsA[256 + t] / cnt - m * m, 0.f);
    float s = g_base[t] * rsqrtf(v + 1e-5f);
    sS[t] = s;
    sT[t] = be_base[t] - m * s;
  }
  __syncthreads();
  {
    int oc = t & 63, part = t >> 6;
    float accw = 0.f;
    for (int ic = part * 64; ic < part * 64 + 64; ++ic) {
      float w = 0.f;
      if (oc < 36) w = W_reg[oc * 256 + ic];
      else if (oc < 54) w = W_cls[(oc - 36) * 256 + ic];
      accw += w * sT[ic];
      W2t2[((size_t)(ic >> 5) * 64 + oc) * 32 + (ic & 31)] = f2bf(w * sS[ic]);
    }
    sP[part][oc] = accw;
  }
  __syncthreads();
  if (t < 64) {
    float bias = 0.f;
    if (t < 36) bias = b_reg[t];
    else if (t < 54) bias = b_cls[t - 36];
    b2[t] = bias + sP[0][t] + sP[1][t] + sP[2][t] + sP[3][t];
  }
}

// ---------------- K3: fused 1x1 heads GEMM (M=131072, N=64, K=256) + z stats ----------------
// BM=256, 512 threads / 8 waves -> 512 blocks (halves latency-bound block-steps
// per CU vs BM=128). Region-major LDS, dbuf 2 x 20KB, R9-style early stage.
// Wave w4 owns pixels 32w4..+31 (acc[2][4]).
__global__ __launch_bounds__(512) void k_mm2(const unsigned short* __restrict__ yt2,
                                             const unsigned short* __restrict__ W2t2,
                                             const float* __restrict__ b2,
                                             unsigned short* __restrict__ zt,
                                             float* __restrict__ statsZ) {
  __shared__ __align__(16) char lds2[40960];   // 2 x (A 16KB | B 4KB)
  int t = threadIdx.x, lane = t & 63, w4 = t >> 6;   // 8 waves
  int row16 = lane & 15, kgl = lane >> 4;
  int pr = lane & 15, pq = lane >> 4;
  size_t pixbase = (size_t)blockIdx.x * 256;

  f32x4 acc[2][4];
#pragma unroll
  for (int m = 0; m < 2; ++m)
#pragma unroll
    for (int nn = 0; nn < 4; ++nn) { f32x4 z = {0.f, 0.f, 0.f, 0.f}; acc[m][nn] = z; }

  // staging: 20 regions/step. A regions 0..15 (pixels 16g..+15), B regions 0..3
  // (ocs 16r..+15). Wave w4: A region w4, A region 8+w4, and (w4<4) B region w4.
  const unsigned short* aSrc0 = yt2 + (pixbase + w4 * 16 + pr) * 32 + pq * 8;
  const unsigned short* aSrc1 = yt2 + (pixbase + 128 + w4 * 16 + pr) * 32 + pq * 8;
  const unsigned short* bSrc  = W2t2 + (size_t)(w4 * 16 + pr) * 32 + pq * 8;

  int aoffA = w4 * 2048 + kgl * 256 + row16 * 16;  // + m*1024 (regions 2w4, 2w4+1)
  int aoffB = kgl * 256 + row16 * 16;              // + nn*1024 (B area +16KB)

  auto STG = [&](int s, int c_) {
    size_t ao = (size_t)s * MPIX * 32;
    size_t bo = (size_t)s * 2048;          // 64 oc * 32
    char* buf = lds2 + c_ * 20480;
    gl16(aSrc0 + ao, buf + w4 * 1024);
    gl16(aSrc1 + ao, buf + (8 + w4) * 1024);
    if (w4 < 4) gl16(bSrc + bo, buf + 16384 + w4 * 1024);
  };

  STG(0, 0);
  int cur = 0;
  for (int s = 0; s < 8; ++s) {
    __syncthreads();                       // drains STG(s); orders reads vs overwrite
    if (s < 7) STG(s + 1, cur ^ 1);
    const char* ab = lds2 + cur * 20480;
    const char* bb = ab + 16384;
    bf16x8 af[2], bfr[4];
#pragma unroll
    for (int m = 0; m < 2; ++m) af[m] = *(const bf16x8*)(ab + aoffA + m * 1024);
#pragma unroll
    for (int nn = 0; nn < 4; ++nn) bfr[nn] = *(const bf16x8*)(bb + aoffB + nn * 1024);
#pragma unroll
    for (int m = 0; m < 2; ++m)
#pragma unroll
      for (int nn = 0; nn < 4; ++nn)
        acc[m][nn] = __builtin_amdgcn_mfma_f32_16x16x32_bf16(af[m], bfr[nn], acc[m][nn], 0, 0, 0);
    cur ^= 1;
  }

  float sums[4] = {0.f, 0.f, 0.f, 0.f}, sumq[4] = {0.f, 0.f, 0.f, 0.f};
#pragma unroll
  for (int nn = 0; nn < 4; ++nn) {
    int oc = nn * 16 + row16;
    float bias = b2[oc];
#pragma unroll
    for (int m = 0; m < 2; ++m) {
#pragma unroll
      for (int j = 0; j < 4; ++j) {
        int p = w4 * 32 + m * 16 + kgl * 4 + j;
        float v = acc[m][nn][j] + bias;
        zt[(pixbase + p) * 64 + oc] = f2bf(v);
        sums[nn] += v; sumq[nn] += v * v;
      }
    }
  }
#pragma unroll
  for (int nn = 0; nn < 4; ++nn) {
    float s1 = sums[nn], s2 = sumq[nn];
    s1 += __shfl_xor(s1, 16); s2 += __shfl_xor(s2, 16);
    s1 += __shfl_xor(s1, 32); s2 += __shfl_xor(s2, 32);
    if (lane < 16) {
      int oc = nn * 16 + lane;
      atomicAdd(&statsZ[oc], s1);
      atomicAdd(&statsZ[64 + oc], s2);
    }
  }
}

// ---------------- K4: finalize z BN scale/shift ----------------
__global__ __launch_bounds__(64) void k_zstat(const float* __restrict__ statsZ,
                                              const float* __restrict__ g_cls,
                                              const float* __restrict__ be_cls,
                                              const float* __restrict__ g_reg,
                                              const float* __restrict__ be_reg,
                                              float* __restrict__ zsc,
                                              float* __restrict__ zsh) {
  int t = threadIdx.x;  // 64
  float g = 1.f, be = 0.f;
  if (t < 36) { g = g_reg[t]; be = be_reg[t]; }
  else if (t < 54) { g = g_cls[t - 36]; be = be_cls[t - 36]; }
  float cnt = (float)MPIX;
  float m = statsZ[t] / cnt;
  float v = fmaxf(statsZ[64 + t] / cnt - m * m, 0.f);
  float s = g * rsqrtf(v + 1e-5f);
  zsc[t] = s;
  zsh[t] = be - m * s;
}

// ---------------- K5: BN-apply + softmax + anchor decode + outputs ----------------
__global__ __launch_bounds__(256) void k_dec(const unsigned short* __restrict__ zt,
                                             const float* __restrict__ zsc,
                                             const float* __restrict__ zsh,
                                             const int* __restrict__ imgsz,
                                             float* __restrict__ out) {
  int p = blockIdx.x * 256 + threadIdx.x;  // 131072
  float lim = (float)imgsz[0];
  float zn[64];
  {
    const uint4* zp4 = (const uint4*)(zt + (size_t)p * 64);
#pragma unroll
    for (int i = 0; i < 8; ++i) {
      uint4 v = zp4[i];
      unsigned a0 = v.x, a1 = v.y, a2 = v.z, a3 = v.w;
      zn[i * 8 + 0] = bf2f((unsigned short)(a0 & 0xffff));
      zn[i * 8 + 1] = bf2f((unsigned short)(a0 >> 16));
      zn[i * 8 + 2] = bf2f((unsigned short)(a1 & 0xffff));
      zn[i * 8 + 3] = bf2f((unsigned short)(a1 >> 16));
      zn[i * 8 + 4] = bf2f((unsigned short)(a2 & 0xffff));
      zn[i * 8 + 5] = bf2f((unsigned short)(a2 >> 16));
      zn[i * 8 + 6] = bf2f((unsigned short)(a3 & 0xffff));
      zn[i * 8 + 7] = bf2f((unsigned short)(a3 >> 16));
    }
#pragma unroll
    for (int i = 0; i < 54; ++i) zn[i] = zn[i] * zsc[i] + zsh[i];
  }
  int rem = p & 16383, h = rem >> 7, w = rem & 127;
  float fx = 16.f * (float)w, fy = 16.f * (float)h;
  size_t kbase = (size_t)p * 9;
  float* fgout = out;
  float* tsout = out + FGCNT;
  float* roout = out + FGCNT + TSCNT;
#pragma unroll
  for (int a = 0; a < 9; ++a) {
    float x1 = 20.f - 0.5f * AW[a] + fx;
    float y1 = 20.f - 0.5f * AH[a] + fy;
    float x2 = 19.f + 0.5f * AW[a] + fx;
    float y2 = 19.f + 0.5f * AH[a] + fy;
    float cx1 = fminf(fmaxf(x1 + zn[4 * a + 0], 0.f), lim);
    float cy1 = fminf(fmaxf(y1 + zn[4 * a + 1], 0.f), lim);
    float cx2 = fminf(fmaxf(x2 + zn[4 * a + 2], 0.f), lim);
    float cy2 = fminf(fmaxf(y2 + zn[4 * a + 3], 0.f), lim);
    float bw = cx2 - cx1, bh = cy2 - cy1;
    float cx = cx1 + 0.5f * bw, cy = cy1 + 0.5f * bh;
    float aw = AW[a] - 1.f, ah = AH[a] - 1.f;
    float acx = 19.5f + fx, acy = 19.5f + fy;
    float tx = (cx - acx) / aw, ty = (cy - acy) / ah;
    float tw = logf(fmaxf(bw / aw, 1e-30f));
    float th = logf(fmaxf(bh / ah, 1e-30f));
    float s0 = zn[36 + 2 * a], s1 = zn[36 + 2 * a + 1];
    float fg = 1.f / (1.f + expf(s0 - s1));
    fgout[kbase + a] = fg;
    size_t o4 = (kbase + a) * 4;
    tsout[o4 + 0] = tx; tsout[o4 + 1] = ty; tsout[o4 + 2] = tw; tsout[o4 + 3] = th;
    roout[o4 + 0] = cx; roout[o4 + 1] = cy; roout[o4 + 2] = bw; roout[o4 + 3] = bh;
  }
}

// ---------------- launch ----------------
extern "C" void kernel_launch(void* const* d_in, const int* in_sizes, int n_in,
                              void* d_out, int out_size, void* d_ws, size_t ws_size,
                              hipStream_t stream) {
  const float* x   = (const float*)d_in[0];
  const float* Wb  = (const float*)d_in[1];
  const float* bb  = (const float*)d_in[2];
  const float* gb  = (const float*)d_in[3];
  const float* beb = (const float*)d_in[4];
  const float* Wc  = (const float*)d_in[5];
  const float* bc  = (const float*)d_in[6];
  const float* gc  = (const float*)d_in[7];
  const float* bec = (const float*)d_in[8];
  const float* Wr  = (const float*)d_in[9];
  const float* br  = (const float*)d_in[10];
  const float* gr  = (const float*)d_in[11];
  const float* ber = (const float*)d_in[12];
  const int* imgsz = (const int*)d_in[13];

  char* ws = (char*)d_ws;
  const size_t OFF_XTP = 0;                        // 64*130*130*32*2 = 69,222,400
  const size_t OFF_Y   = 69222400;                 // 8*131072*32*2   = 67,108,864
  const size_t OFF_Z   = 136331264;                // 131072*64*2     = 16,777,216
  const size_t OFF_WT  = 153108480;                // 72*256*32*2     =  1,179,648
  const size_t OFF_W2  = 154288128;                // 8*64*32*2       =     32,768
  const size_t OFF_S   = 154320896;                // small area
  unsigned short* xt2  = (unsigned short*)(ws + OFF_XTP);
  unsigned short* yt2  = (unsigned short*)(ws + OFF_Y);
  unsigned short* zt   = (unsigned short*)(ws + OFF_Z);
  unsigned short* Wt2  = (unsigned short*)(ws + OFF_WT);
  unsigned short* W2t2 = (unsigned short*)(ws + OFF_W2);
  float* b2     = (float*)(ws + OFF_S);            // 64 f
  float* statsA = (float*)(ws + OFF_S + 256);      // 512 f
  float* statsZ = (float*)(ws + OFF_S + 2304);     // 128 f
  float* zsc    = (float*)(ws + OFF_S + 2816);     // 64 f
  float* zsh    = (float*)(ws + OFF_S + 3072);     // 64 f
  float* out = (float*)d_out;

  hipMemsetAsync(statsA, 0, (512 + 128) * sizeof(float), stream);
  k_wt  <<<2304, 256, 0, stream>>>(Wb, Wt2);
  k_tr  <<<8192, 256, 0, stream>>>(x, xt2);
  k_bord<<<516, 256, 0, stream>>>(xt2);
  k_conv<<<2048, 256, 0, stream>>>(xt2, Wt2, bb, yt2, statsA);
  k_fold<<<1, 256, 0, stream>>>(statsA, gb, beb, Wc, bc, Wr, br, W2t2, b2);
  k_mm2 <<<512, 512, 0, stream>>>(yt2, W2t2, b2, zt, statsZ);
  k_zstat<<<1, 64, 0, stream>>>(statsZ, gc, bec, gr, ber, zsc, zsh);
  k_dec <<<512, 256, 0, stream>>>(zt, zsc, zsh, imgsz, out);
}